// Round 8
// baseline (325.748 us; speedup 1.0000x reference)
//
#include <hip/hip_runtime.h>
#include <hip/hip_cooperative_groups.h>
#include <math.h>

// GIN v14: v13's cooperative mega-kernel, made robust. v13's zero-output +
// 2s fail = hipLaunchCooperativeKernel REJECTED the hard-coded 768-block
// grid (co-residency validation) and the error was unchecked. v14:
// (1) grid sized by hipOccupancyMaxActiveBlocksPerMultiprocessor x CU
//     count (pure driver queries, capture-safe); all phases grid-stride.
// (2) coop only if grid >= 512 (else agg occupancy would crater);
// (3) fallback multi-kernel path (v12-equivalent, same __device__ bodies,
//     right-sized LDS per wrapper) when coop can't fit or errors.

namespace cg = cooperative_groups;

#define NNODES 100000
#define NEDGES 1600000
#define NGRAPHS 512
#define NB 782
#define NBH 1564
#define BCAP 2560
#define LCAP 2304
#define GOFS 72
#define CHUNK 4096
#define NCHUNKS 391
#define NGEMM 1563
#define HSTR 72   // H1/H2 row stride (u16): 144B
#define XSTR 136  // gemm x-tile row stride (u16)
#define NTHR 512
#define NSETUP 104

typedef unsigned short u16;
typedef unsigned int u32;
typedef __attribute__((ext_vector_type(8))) short short8;
typedef __attribute__((ext_vector_type(4))) float f32x4;

__device__ __forceinline__ u16 f2b(float f) {
  union { float f; unsigned u; } v;
  v.f = f;
  unsigned r = v.u + 0x7FFF + ((v.u >> 16) & 1);
  return (u16)(r >> 16);
}
__device__ __forceinline__ float b2f(u16 h) {
  union { unsigned u; float f; } v;
  v.u = ((unsigned)h) << 16;
  return v.f;
}
#define LDS_FENCE() __asm__ volatile("s_waitcnt lgkmcnt(0)" ::: "memory")

struct GinParams {
  const int* src; const int* dst; const int* batch; const float* x;
  const float* w1g; const float* w2a; const float* w2b; const float* w2c;
  const float* w1b; const float* w1c;
  const float* b1_0; const float* b1_1; const float* b1_2;
  const float* b2_0; const float* b2_1; const float* b2_2;
  const float* eps;
  const float* fc1w; const float* fc1b; const float* fc2w; const float* fc2b;
  float* out;
  int* gcur; int* st; int* glofs; int* glcol;
  u16* w1f; u16* w2f0; u16* w2f1; u16* w2f2; u16* w1nf1; u16* w1nf2;
  u16* zA; u16* zB; float* gsum; float* gmax; int* gcnt;
};

// S layout (41216 B union):
//  bin : staged@0(16384) stb@16384(8192) hist@24576(3128) lofs@27712(3132)
//        lcur@30848(3128) gbase@33984(3128) sd@37120(4096)
//  gemm: w1h@0(16384) Xt@16384(17408)
//  csr : lcol@0(9216) lhist@9216 lofs@9472 lcur@9736 ssc@9992 (end 10248)
//  agg : lcol/H2@0(9216) H1/w1nh@9216(9216) w2h@18432(8192) b2s@26624(256)
//        lofs@26880(260) bt@27144(256) (end 27400)
//  head: gs@0(18432)

__device__ __forceinline__ int lb_dev(const int* __restrict__ a, int n, int v) {
  int lo = 0, hi = n;
  while (lo < hi) {
    int m = (lo + hi) >> 1;
    if (a[m] < v) lo = m + 1; else hi = m;
  }
  return lo;
}

__device__ __forceinline__ void setup_body(const GinParams& p, int vb) {
  const int tid = threadIdx.x;
  if (vb == 0) {  // w1: 128x64 swizzle
    for (int i = tid; i < 8192; i += NTHR) {
      int jj = i & 7, lane = (i >> 3) & 63, c = i >> 9;
      int nt = c >> 2, ks = c & 3;
      int mrow = lane & 15, quad = lane >> 4;
      p.w1f[i] = f2b(p.w1g[(ks * 32 + quad * 8 + jj) * 64 + nt * 16 + mrow]);
    }
  } else if (vb < 6) {  // 64x64 weights
    const float* s = (vb == 1) ? p.w2a : (vb == 2) ? p.w2b
                     : (vb == 3) ? p.w2c : (vb == 4) ? p.w1b : p.w1c;
    u16* d = (vb == 1) ? p.w2f0 : (vb == 2) ? p.w2f1
             : (vb == 3) ? p.w2f2 : (vb == 4) ? p.w1nf1 : p.w1nf2;
    for (int i = tid; i < 4096; i += NTHR) {
      int jj = i & 7, lane = (i >> 3) & 63, c = i >> 9;
      int nt = c >> 1, ks = c & 1;
      int mrow = lane & 15, quad = lane >> 4;
      d[i] = f2b(s[(ks * 32 + quad * 8 + jj) * 64 + nt * 16 + mrow]);
    }
  } else if (vb == 6) {  // gcur zero + sentinel rows
    for (int i = tid; i < NB; i += NTHR) p.gcur[i] = 0;
    if (tid < 64) p.zA[(size_t)NNODES * 64 + tid] = 0;
    else if (tid < 128) p.zB[(size_t)NNODES * 64 + (tid - 64)] = 0;
  } else if (vb == 7) {  // per-graph node counts
    for (int g = tid; g < NGRAPHS; g += NTHR)
      p.gcnt[g] = lb_dev(p.batch, NNODES, g + 1) - lb_dev(p.batch, NNODES, g);
  } else {  // zero gsum||gmax: 96 vblocks x 512 x 16B = 2x393216B
    ((int4*)p.gsum)[(vb - 8) * NTHR + tid] = make_int4(0, 0, 0, 0);
  }
}

__device__ __forceinline__ void bin_body(const GinParams& p, char* S, int cb) {
  int* staged = (int*)S;
  u16* stb = (u16*)(S + 16384);
  int* hist = (int*)(S + 24576);
  int* lofs = (int*)(S + 27712);
  int* lcur = (int*)(S + 30848);
  int* gbase = (int*)(S + 33984);
  int* sd = (int*)(S + 37120);
  const int t = threadIdx.x;
  const int e0 = cb * CHUNK;
  const int n = min(CHUNK, NEDGES - e0);

  for (int i = t; i < NB; i += NTHR) hist[i] = 0;
  __syncthreads();

  int pk[8];
  int bk[8];
#pragma unroll
  for (int k = 0; k < 8; ++k) {
    int i = t + k * NTHR;
    if (i < n) {
      int s = p.src[e0 + i];
      int d = p.dst[e0 + i];
      int b = d >> 7;
      pk[k] = (s << 7) | (d & 127);
      bk[k] = b;
      atomicAdd(&hist[b], 1);
    } else {
      bk[k] = -1;
    }
  }
  __syncthreads();

  sd[t] = (t < NB) ? hist[t] : 0;
  sd[t + 512] = (t + 512 < NB) ? hist[t + 512] : 0;
  __syncthreads();
  for (int off = 1; off < 1024; off <<= 1) {
    int v0 = (t >= off) ? sd[t - off] : 0;
    int v1 = (t + 512 >= off) ? sd[t + 512 - off] : 0;
    __syncthreads();
    sd[t] += v0;
    sd[t + 512] += v1;
    __syncthreads();
  }
  if (t == 0) lofs[0] = 0;
  for (int i = t; i < NB; i += NTHR) {
    int inc = sd[i];
    int c = hist[i];
    lofs[i + 1] = inc;
    lcur[i] = inc - c;
    gbase[i] = c ? atomicAdd(&p.gcur[i], c) : 0;  // zero-based cursor
  }
  __syncthreads();

#pragma unroll
  for (int k = 0; k < 8; ++k) {
    if (bk[k] >= 0) {
      int r = atomicAdd(&lcur[bk[k]], 1);
      staged[r] = pk[k];
      stb[r] = (u16)bk[k];
    }
  }
  __syncthreads();

  for (int i = t; i < n; i += NTHR) {
    int b = stb[i];
    p.st[(size_t)b * BCAP + gbase[b] + (i - lofs[b])] = staged[i];
  }
}

__device__ __forceinline__ void gemm_body(const GinParams& p, char* S,
                                          int tile) {
  u16* w1h = (u16*)S;
  u16* Xt = (u16*)(S + 16384);
  const int tid = threadIdx.x;
  const int base = tile * 64;
  for (int i = tid; i < 1024; i += NTHR)
    ((int4*)w1h)[i] = ((const int4*)p.w1f)[i];
  for (int i = tid; i < 2048; i += NTHR) {
    int n = i >> 5, c4 = i & 31;
    int nn = base + n;
    float4 v = make_float4(0.f, 0.f, 0.f, 0.f);
    if (nn < NNODES) v = *(const float4*)&p.x[(size_t)nn * 128 + 4 * c4];
    u32 p0 = (u32)f2b(v.x) | ((u32)f2b(v.y) << 16);
    u32 p1 = (u32)f2b(v.z) | ((u32)f2b(v.w) << 16);
    *(u32*)&Xt[n * XSTR + 4 * c4] = p0;
    *(u32*)&Xt[n * XSTR + 4 * c4 + 2] = p1;
  }
  __syncthreads();
  const int lane = tid & 63;
  const int wv = tid >> 6;
  const int mrow = lane & 15;
  const int quad = lane >> 4;
  f32x4 accs[4];
  if (wv < 4) {
#pragma unroll
    for (int nt = 0; nt < 4; ++nt) {
      f32x4 acc = {0.f, 0.f, 0.f, 0.f};
#pragma unroll
      for (int ks = 0; ks < 4; ++ks) {
        short8 afr =
            *(const short8*)&Xt[(wv * 16 + mrow) * XSTR + ks * 32 + quad * 8];
        short8 bfr = *(const short8*)&w1h[((nt * 4 + ks) * 64 + lane) * 8];
        acc = __builtin_amdgcn_mfma_f32_16x16x32_bf16(afr, bfr, acc, 0, 0, 0);
      }
      accs[nt] = acc;
    }
  }
  __syncthreads();
  u16* Zt = Xt;
  if (wv < 4) {
#pragma unroll
    for (int nt = 0; nt < 4; ++nt)
#pragma unroll
      for (int r = 0; r < 4; ++r)
        Zt[(wv * 16 + quad * 4 + r) * HSTR + nt * 16 + mrow] =
            f2b(accs[nt][r]);
  }
  __syncthreads();
  for (int i = tid; i < 2048; i += NTHR) {
    int n = i >> 5, kk = i & 31;
    int nn = base + n;
    if (nn < NNODES)
      *(u32*)&p.zA[(size_t)nn * 64 + 2 * kk] = *(u32*)&Zt[n * HSTR + 2 * kk];
  }
}

__device__ __forceinline__ void csr_body(const GinParams& p, char* S,
                                         int blk) {
  int* lcol = (int*)S;
  int* lhist = (int*)(S + 9216);
  int* lofs = (int*)(S + 9472);
  int* lcur = (int*)(S + 9736);
  int* ssc = (int*)(S + 9992);
  const int tid = threadIdx.x;
  const int bkt = blk >> 1;
  const int half = blk & 1;
  const int ofs = bkt * BCAP;
  const int cnt = min(p.gcur[bkt], BCAP);

  if (tid < 64) lhist[tid] = 0;
  __syncthreads();
  for (int i = tid; i < cnt; i += NTHR) {
    int d7 = p.st[ofs + i] & 127;
    if ((d7 >> 6) == half) atomicAdd(&lhist[d7 & 63], 1);
  }
  __syncthreads();
  if (tid < 64) ssc[tid] = (lhist[tid] + 15) & ~15;
  __syncthreads();
  for (int off = 1; off < 64; off <<= 1) {
    int v = (tid < 64 && tid >= off) ? ssc[tid - off] : 0;
    __syncthreads();
    if (tid < 64) ssc[tid] += v;
    __syncthreads();
  }
  if (tid < 64) {
    lofs[tid + 1] = ssc[tid];
    lcur[tid] = ssc[tid] - ((lhist[tid] + 15) & ~15);
  }
  if (tid == 0) lofs[0] = 0;
  __syncthreads();
  for (int i = tid; i < cnt; i += NTHR) {
    int pkt = p.st[ofs + i];
    int d7 = pkt & 127;
    if ((d7 >> 6) == half) {
      int r = atomicAdd(&lcur[d7 & 63], 1);
      if (r < LCAP) lcol[r] = pkt >> 7;
    }
  }
  __syncthreads();
  if (tid < 64) {
    int re = min(lofs[tid + 1], LCAP);
    for (int r = lcur[tid]; r < re; ++r) lcol[r] = NNODES;
  }
  __syncthreads();
  if (tid < 65) p.glofs[blk * GOFS + tid] = min(lofs[tid], LCAP);
  int L = min(lofs[64], LCAP);
  int4* gdst = (int4*)(p.glcol + (size_t)blk * LCAP);
  const int4* lsrc = (const int4*)lcol;
  for (int i = tid; i < (L >> 2); i += NTHR) gdst[i] = lsrc[i];
}

// Caller must have staged w2h (S+18432) and b2s (S+26624) and synced.
__device__ __forceinline__ void agg_body(const GinParams& p, char* S, int blk,
                                         int li, const u16* zin, u16* zn,
                                         const float* b1p, const u16* w1nf,
                                         bool hasnext) {
  int* lcol = (int*)S;
  u16* H2 = (u16*)S;
  u16* H1 = (u16*)(S + 9216);
  u16* w1nh = (u16*)(S + 9216);
  u16* w2h = (u16*)(S + 18432);
  float* b2s = (float*)(S + 26624);
  int* lofs = (int*)(S + 26880);
  int* bt = (int*)(S + 27144);
  const int tid = threadIdx.x;
  const int lane = tid & 63;
  const int wv = tid >> 6;
  const int sub = lane >> 5;
  const int fl = lane & 31;
  const int f = 2 * fl + sub;
  const int base = blk << 6;

  if (tid < 64) {
    int nn = base + tid;
    bt[tid] = (nn < NNODES) ? p.batch[nn] : -1;
  }
  if (tid < 65) lofs[tid] = p.glofs[blk * GOFS + tid];
  __syncthreads();
  const int L = lofs[64];
  {
    int4* ldst = (int4*)lcol;
    const int4* gsrc = (const int4*)(p.glcol + (size_t)blk * LCAP);
    for (int i = tid; i < (L >> 2); i += NTHR) ldst[i] = gsrc[i];
  }
  __syncthreads();

  const float e1 = 1.0f + p.eps[li];
  const float b1v = b1p[f];
  const int n0g = wv * 8;

#pragma unroll 1
  for (int j = 0; j < 8; ++j) {
    int ln = n0g + j;
    int nn = base + ln;
    int sn = (nn < NNODES) ? nn : NNODES;
    int rs = lofs[ln], re = lofs[ln + 1];
    float sa0 = 0.f, sa1 = 0.f, sa2 = 0.f, sa3 = 0.f;
    float sb0 = 0.f, sb1 = 0.f, sb2 = 0.f, sb3 = 0.f;
    for (int e = rs; e < re; e += 16) {
      int c0 = lcol[e + 0 + sub];
      int c1 = lcol[e + 2 + sub];
      int c2 = lcol[e + 4 + sub];
      int c3 = lcol[e + 6 + sub];
      int c4 = lcol[e + 8 + sub];
      int c5 = lcol[e + 10 + sub];
      int c6 = lcol[e + 12 + sub];
      int c7 = lcol[e + 14 + sub];
      u32 v0 = *(const u32*)&zin[(size_t)c0 * 64 + 2 * fl];
      u32 v1 = *(const u32*)&zin[(size_t)c1 * 64 + 2 * fl];
      u32 v2 = *(const u32*)&zin[(size_t)c2 * 64 + 2 * fl];
      u32 v3 = *(const u32*)&zin[(size_t)c3 * 64 + 2 * fl];
      u32 v4 = *(const u32*)&zin[(size_t)c4 * 64 + 2 * fl];
      u32 v5 = *(const u32*)&zin[(size_t)c5 * 64 + 2 * fl];
      u32 v6 = *(const u32*)&zin[(size_t)c6 * 64 + 2 * fl];
      u32 v7 = *(const u32*)&zin[(size_t)c7 * 64 + 2 * fl];
      sa0 += __uint_as_float(v0 << 16);
      sb0 += __uint_as_float(v0 & 0xffff0000u);
      sa1 += __uint_as_float(v1 << 16);
      sb1 += __uint_as_float(v1 & 0xffff0000u);
      sa2 += __uint_as_float(v2 << 16);
      sb2 += __uint_as_float(v2 & 0xffff0000u);
      sa3 += __uint_as_float(v3 << 16);
      sb3 += __uint_as_float(v3 & 0xffff0000u);
      sa0 += __uint_as_float(v4 << 16);
      sb0 += __uint_as_float(v4 & 0xffff0000u);
      sa1 += __uint_as_float(v5 << 16);
      sb1 += __uint_as_float(v5 & 0xffff0000u);
      sa2 += __uint_as_float(v6 << 16);
      sb2 += __uint_as_float(v6 & 0xffff0000u);
      sa3 += __uint_as_float(v7 << 16);
      sb3 += __uint_as_float(v7 & 0xffff0000u);
    }
    float sa = (sa0 + sa1) + (sa2 + sa3);
    float sb = (sb0 + sb1) + (sb2 + sb3);
    sa += __shfl_xor(sa, 32);
    sb += __shfl_xor(sb, 32);
    float sum = sub ? sb : sa;
    float self = b2f(zin[(size_t)sn * 64 + f]);
    float h = fmaxf(sum + e1 * self + b1v, 0.f);
    H1[ln * HSTR + f] = f2b(h);
  }
  __syncthreads();  // lcol reads done block-wide; H1 fully written

  const int mrow = lane & 15;
  const int quad = lane >> 4;
  if (wv < 4) {
    f32x4 m1[4];
#pragma unroll
    for (int nt = 0; nt < 4; ++nt) {
      f32x4 acc = {0.f, 0.f, 0.f, 0.f};
#pragma unroll
      for (int ks = 0; ks < 2; ++ks) {
        short8 afr =
            *(const short8*)&H1[(wv * 16 + mrow) * HSTR + ks * 32 + quad * 8];
        short8 bfr = *(const short8*)&w2h[((nt * 2 + ks) * 64 + lane) * 8];
        acc = __builtin_amdgcn_mfma_f32_16x16x32_bf16(afr, bfr, acc, 0, 0, 0);
      }
      m1[nt] = acc;
    }
    LDS_FENCE();
#pragma unroll
    for (int nt = 0; nt < 4; ++nt) {
      float bb = b2s[nt * 16 + mrow];
#pragma unroll
      for (int r = 0; r < 4; ++r)
        H2[(wv * 16 + quad * 4 + r) * HSTR + nt * 16 + mrow] =
            f2b(fmaxf(m1[nt][r] + bb, 0.f));
    }
  }
  __syncthreads();  // H2 visible to all waves for pooling

  {
    const int n0p = wv * 8;
    float s = 0.f, m = 0.f;
    int cur = bt[n0p];
#pragma unroll 1
    for (int j = 0; j < 8; ++j) {
      int b = bt[n0p + j];
      if (b != cur) {
        if (cur >= 0) {
          atomicAdd(&p.gsum[cur * 192 + li * 64 + lane], s);
          atomicMax((u32*)&p.gmax[cur * 192 + li * 64 + lane],
                    __float_as_uint(m));
        }
        s = 0.f;
        m = 0.f;
        cur = b;
      }
      if (b >= 0) {
        float v = b2f(H2[(n0p + j) * HSTR + lane]);
        s += v;
        m = fmaxf(m, v);
      }
    }
    if (cur >= 0) {
      atomicAdd(&p.gsum[cur * 192 + li * 64 + lane], s);
      atomicMax((u32*)&p.gmax[cur * 192 + li * 64 + lane],
                __float_as_uint(m));
    }
  }

  if (hasnext) {
    __syncthreads();  // pooling reads of H2 done; H1 fully dead
    for (int i = tid; i < 512; i += NTHR)
      ((int4*)w1nh)[i] = ((const int4*)w1nf)[i];
    __syncthreads();
    if (wv < 4) {
      f32x4 m2[4];
#pragma unroll
      for (int nt = 0; nt < 4; ++nt) {
        f32x4 acc = {0.f, 0.f, 0.f, 0.f};
#pragma unroll
        for (int ks = 0; ks < 2; ++ks) {
          short8 afr =
              *(const short8*)&H2[(wv * 16 + mrow) * HSTR + ks * 32 + quad * 8];
          short8 bfr = *(const short8*)&w1nh[((nt * 2 + ks) * 64 + lane) * 8];
          acc = __builtin_amdgcn_mfma_f32_16x16x32_bf16(afr, bfr, acc, 0, 0, 0);
        }
        m2[nt] = acc;
      }
      LDS_FENCE();
#pragma unroll
      for (int nt = 0; nt < 4; ++nt)
#pragma unroll
        for (int r = 0; r < 4; ++r)
          H2[(wv * 16 + quad * 4 + r) * HSTR + nt * 16 + mrow] =
              f2b(m2[nt][r]);
    }
    __syncthreads();
    for (int i = tid; i < 2048; i += NTHR) {
      int n = i >> 5, kk = i & 31;
      int nn = base + n;
      if (nn < NNODES)
        *(u32*)&zn[(size_t)nn * 64 + 2 * kk] = *(u32*)&H2[n * HSTR + 2 * kk];
    }
  }
}

__device__ __forceinline__ void head_body(const GinParams& p, char* S,
                                          int vb) {
  float* gs = (float*)S;  // 8*576 floats = 18432 B
  const int tid = threadIdx.x;
  int g0 = vb * 8;
  for (int i = tid; i < 8 * 192; i += NTHR) {
    int w = i / 192, idx = i - w * 192;
    int gi = g0 + w;
    float Sv = p.gsum[gi * 192 + idx];
    float M = p.gmax[gi * 192 + idx];
    float C = (float)p.gcnt[gi];
    gs[w * 576 + idx] = Sv / fmaxf(C, 1.0f);
    gs[w * 576 + 192 + idx] = M;
    gs[w * 576 + 384 + idx] = Sv;
  }
  __syncthreads();
  int wv = tid >> 6, lane = tid & 63;
  int gi = g0 + wv;
  const float* grow = &gs[wv * 576];
  float acc = p.fc1b[lane];
#pragma unroll 8
  for (int k = 0; k < 576; ++k) acc += grow[k] * p.fc1w[k * 64 + lane];
  acc = fmaxf(acc, 0.f);
  float p0 = acc * p.fc2w[lane * 2 + 0];
  float p1 = acc * p.fc2w[lane * 2 + 1];
  for (int off = 32; off; off >>= 1) {
    p0 += __shfl_down(p0, off);
    p1 += __shfl_down(p1, off);
  }
  if (lane == 0) {
    p.out[gi * 2 + 0] = 1.f / (1.f + __expf(-(p0 + p.fc2b[0])));
    p.out[gi * 2 + 1] = 1.f / (1.f + __expf(-(p1 + p.fc2b[1])));
  }
}

// ---------------- cooperative mega-kernel (grid-stride phases) ------------

__global__ __launch_bounds__(NTHR, 6) void mega_kernel(GinParams p) {
  cg::grid_group grid = cg::this_grid();
  __shared__ __align__(16) char S[41216];
  const int tid = threadIdx.x;
  const int bid = blockIdx.x;
  const int G = gridDim.x;

  // P0: setup
  for (int vb = bid; vb < NSETUP; vb += G) setup_body(p, vb);
  __threadfence();
  grid.sync();

  // P1: bin || gemm (independent)
  for (int vb = bid; vb < NCHUNKS + NGEMM; vb += G) {
    __syncthreads();
    if (vb < NCHUNKS)
      bin_body(p, S, vb);
    else
      gemm_body(p, S, vb - NCHUNKS);
  }
  __threadfence();
  grid.sync();

  // P2: csr
  for (int vb = bid; vb < NBH; vb += G) {
    __syncthreads();
    csr_body(p, S, vb);
  }
  __threadfence();
  grid.sync();

  // P3..P5: agg layers
  for (int li = 0; li < 3; ++li) {
    const u16* zin = (li == 1) ? p.zB : p.zA;
    u16* zn = (li == 0) ? p.zB : (li == 1) ? p.zA : (u16*)nullptr;
    const u16* w2f = (li == 0) ? p.w2f0 : (li == 1) ? p.w2f1 : p.w2f2;
    const u16* w1nf = (li == 0) ? p.w1nf1 : p.w1nf2;
    const float* b1p = (li == 0) ? p.b1_0 : (li == 1) ? p.b1_1 : p.b1_2;
    const float* b2p = (li == 0) ? p.b2_0 : (li == 1) ? p.b2_1 : p.b2_2;
    u16* w2h = (u16*)(S + 18432);
    float* b2s = (float*)(S + 26624);
    __syncthreads();
    for (int i = tid; i < 512; i += NTHR)
      ((int4*)w2h)[i] = ((const int4*)w2f)[i];
    if (tid < 64) b2s[tid] = b2p[tid];
    __syncthreads();
    for (int vb = bid; vb < NBH; vb += G) {
      agg_body(p, S, vb, li, zin, zn, b1p, w1nf, li < 2);
      __syncthreads();
    }
    __threadfence();
    grid.sync();
  }

  // P6: head
  for (int vb = bid; vb < NGRAPHS / 8; vb += G) {
    __syncthreads();
    head_body(p, S, vb);
  }
}

// ---------------- fallback wrappers (v12-equivalent pipeline) -------------

__global__ __launch_bounds__(NTHR) void setup_wrap(GinParams p) {
  setup_body(p, blockIdx.x);
}
__global__ __launch_bounds__(NTHR) void bin_wrap(GinParams p) {
  __shared__ __align__(16) char S[41216];
  bin_body(p, S, blockIdx.x);
}
__global__ __launch_bounds__(NTHR) void gemm_wrap(GinParams p) {
  __shared__ __align__(16) char S[33792];
  gemm_body(p, S, blockIdx.x);
}
__global__ __launch_bounds__(NTHR) void csr_wrap(GinParams p) {
  __shared__ __align__(16) char S[10248];
  csr_body(p, S, blockIdx.x);
}
template <bool HN>
__global__ __launch_bounds__(NTHR, 8) void agg_wrap(GinParams p, int li,
                                                    const u16* zin, u16* zn,
                                                    const float* b1p,
                                                    const u16* w1nf,
                                                    const u16* w2f,
                                                    const float* b2p) {
  __shared__ __align__(16) char S[27400];
  u16* w2h = (u16*)(S + 18432);
  float* b2s = (float*)(S + 26624);
  for (int i = threadIdx.x; i < 512; i += NTHR)
    ((int4*)w2h)[i] = ((const int4*)w2f)[i];
  if (threadIdx.x < 64) b2s[threadIdx.x] = b2p[threadIdx.x];
  __syncthreads();
  agg_body(p, S, blockIdx.x, li, zin, zn, b1p, w1nf, HN);
}
__global__ __launch_bounds__(NTHR) void head_wrap(GinParams p) {
  __shared__ __align__(16) char S[18432];
  head_body(p, S, blockIdx.x);
}

// ---------------- launch ----------------

static int g_coop_grid = -2;  // -2 unknown, 0 disabled, >0 grid size

extern "C" void kernel_launch(void* const* d_in, const int* in_sizes, int n_in,
                              void* d_out, int out_size, void* d_ws,
                              size_t ws_size, hipStream_t stream) {
  const float* x = (const float*)d_in[0];
  const int* ei = (const int*)d_in[1];
  const int* src = ei;
  const int* dst = ei + NEDGES;
  const int* batch = (const int*)d_in[2];
  const float* lw1[3] = {(const float*)d_in[3], (const float*)d_in[7],
                         (const float*)d_in[11]};
  const float* lb1[3] = {(const float*)d_in[4], (const float*)d_in[8],
                         (const float*)d_in[12]};
  const float* lw2[3] = {(const float*)d_in[5], (const float*)d_in[9],
                         (const float*)d_in[13]};
  const float* lb2[3] = {(const float*)d_in[6], (const float*)d_in[10],
                         (const float*)d_in[14]};
  const float* eps = (const float*)d_in[15];
  const float* fc1w = (const float*)d_in[16];
  const float* fc1b = (const float*)d_in[17];
  const float* fc2w = (const float*)d_in[18];
  const float* fc2b = (const float*)d_in[19];
  float* out = (float*)d_out;

  char* p = (char*)d_ws;
  auto carve = [&](size_t bytes) {
    void* r = (void*)p;
    p += (bytes + 1023) & ~(size_t)1023;
    return r;
  };
  float* gsum = (float*)carve((size_t)NGRAPHS * 192 * 4);
  float* gmax = (float*)carve((size_t)NGRAPHS * 192 * 4);
  int* gcur = (int*)carve((NB + 4) * 4);
  int* st = (int*)carve((size_t)NB * BCAP * 4);
  int* glofs = (int*)carve((size_t)NBH * GOFS * 4);
  int* glcol = (int*)carve((size_t)NBH * LCAP * 4);
  u16* w1f = (u16*)carve(8192 * 2);
  u16* w2f0 = (u16*)carve(4096 * 2);
  u16* w2f1 = (u16*)carve(4096 * 2);
  u16* w2f2 = (u16*)carve(4096 * 2);
  u16* w1nf1 = (u16*)carve(4096 * 2);
  u16* w1nf2 = (u16*)carve(4096 * 2);
  u16* zA = (u16*)carve((size_t)(NNODES + 1) * 64 * 2);
  u16* zB = (u16*)carve((size_t)(NNODES + 1) * 64 * 2);
  int* gcnt = (int*)carve(NGRAPHS * 4);

  GinParams prm;
  prm.src = src; prm.dst = dst; prm.batch = batch; prm.x = x;
  prm.w1g = lw1[0]; prm.w2a = lw2[0]; prm.w2b = lw2[1]; prm.w2c = lw2[2];
  prm.w1b = lw1[1]; prm.w1c = lw1[2];
  prm.b1_0 = lb1[0]; prm.b1_1 = lb1[1]; prm.b1_2 = lb1[2];
  prm.b2_0 = lb2[0]; prm.b2_1 = lb2[1]; prm.b2_2 = lb2[2];
  prm.eps = eps;
  prm.fc1w = fc1w; prm.fc1b = fc1b; prm.fc2w = fc2w; prm.fc2b = fc2b;
  prm.out = out;
  prm.gcur = gcur; prm.st = st; prm.glofs = glofs; prm.glcol = glcol;
  prm.w1f = w1f; prm.w2f0 = w2f0; prm.w2f1 = w2f1; prm.w2f2 = w2f2;
  prm.w1nf1 = w1nf1; prm.w1nf2 = w1nf2;
  prm.zA = zA; prm.zB = zB; prm.gsum = gsum; prm.gmax = gmax; prm.gcnt = gcnt;

  if (g_coop_grid == -2) {  // one-time sizing (pure driver queries)
    int perCU = 0, cus = 0, coop = 0, dev = 0;
    (void)hipGetDevice(&dev);
    hipError_t e1 = hipOccupancyMaxActiveBlocksPerMultiprocessor(
        &perCU, (const void*)mega_kernel, NTHR, 0);
    hipError_t e2 =
        hipDeviceGetAttribute(&cus, hipDeviceAttributeMultiprocessorCount, dev);
    hipError_t e3 = hipDeviceGetAttribute(
        &coop, hipDeviceAttributeCooperativeLaunch, dev);
    int g = (e1 == hipSuccess && e2 == hipSuccess && e3 == hipSuccess && coop)
                ? perCU * cus
                : 0;
    if (g > NBH) g = NBH;
    g_coop_grid = (g >= 512) ? g : 0;
  }

  if (g_coop_grid > 0) {
    void* args[] = {(void*)&prm};
    hipError_t e = hipLaunchCooperativeKernel(
        (void*)mega_kernel, dim3(g_coop_grid), dim3(NTHR), args, 0, stream);
    if (e == hipSuccess) return;
    g_coop_grid = 0;  // never retry; fall through to multi-kernel path
  }

  setup_wrap<<<NSETUP, NTHR, 0, stream>>>(prm);
  bin_wrap<<<NCHUNKS, NTHR, 0, stream>>>(prm);
  gemm_wrap<<<NGEMM, NTHR, 0, stream>>>(prm);
  csr_wrap<<<NBH, NTHR, 0, stream>>>(prm);
  agg_wrap<true><<<NBH, NTHR, 0, stream>>>(prm, 0, zA, zB, lb1[0], w1nf1,
                                           w2f0, lb2[0]);
  agg_wrap<true><<<NBH, NTHR, 0, stream>>>(prm, 1, zB, zA, lb1[1], w1nf2,
                                           w2f1, lb2[1]);
  agg_wrap<false><<<NBH, NTHR, 0, stream>>>(prm, 2, zA, (u16*)nullptr, lb1[2],
                                            w1nf2, w2f2, lb2[2]);
  head_wrap<<<NGRAPHS / 8, NTHR, 0, stream>>>(prm);
}

// Round 9
// 307.611 us; speedup vs baseline: 1.0590x; 1.0590x over previous
//
#include <hip/hip_runtime.h>
#include <math.h>

// GIN v15: dependency-aware fusion, 6 dispatches. v14 evidence: coop
// mega-kernel = 1458us (grid.sync on gfx950 >> launch gaps; VALUBusy 5.7%)
// -> deleted. Stream-ordered kernels serialize, so overlap independent
// work via block-range splits instead:
//  1) bingemm: bin (blocks 0..390) || gemm (391..) - independent outputs,
//     both fit the 41.5KB LDS union at 512thr; gemm hides under bin.
//  2) aggcsr0: csr fused into agg layer 0 - csr block b's layer-0 consumer
//     is exactly agg block b; build lcol/lofs in LDS, write glofs/glcol
//     for layers 1-2, gather straight from LDS (saves csr dispatch + 14MB
//     glcol read-back; csr VALU work hides in agg's latency-idle slots).
//  3) rest = proven v14-fallback bodies (512thr, passed @325.7).
// setup, bingemm, aggcsr0, agg1, agg2, head.

#define NNODES 100000
#define NEDGES 1600000
#define NGRAPHS 512
#define NB 782
#define NBH 1564
#define BCAP 2560
#define LCAP 2304
#define GOFS 72
#define CHUNK 4096
#define NCHUNKS 391
#define NGEMM 1563
#define HSTR 72   // H1/H2 row stride (u16): 144B
#define XSTR 136  // gemm x-tile row stride (u16)
#define NTHR 512
#define NSETUP 104

typedef unsigned short u16;
typedef unsigned int u32;
typedef __attribute__((ext_vector_type(8))) short short8;
typedef __attribute__((ext_vector_type(4))) float f32x4;

__device__ __forceinline__ u16 f2b(float f) {
  union { float f; unsigned u; } v;
  v.f = f;
  unsigned r = v.u + 0x7FFF + ((v.u >> 16) & 1);
  return (u16)(r >> 16);
}
__device__ __forceinline__ float b2f(u16 h) {
  union { unsigned u; float f; } v;
  v.u = ((unsigned)h) << 16;
  return v.f;
}
#define LDS_FENCE() __asm__ volatile("s_waitcnt lgkmcnt(0)" ::: "memory")

struct GinParams {
  const int* src; const int* dst; const int* batch; const float* x;
  const float* w1g; const float* w2a; const float* w2b; const float* w2c;
  const float* w1b; const float* w1c;
  const float* b1_0; const float* b1_1; const float* b1_2;
  const float* b2_0; const float* b2_1; const float* b2_2;
  const float* eps;
  const float* fc1w; const float* fc1b; const float* fc2w; const float* fc2b;
  float* out;
  int* gcur; int* st; int* glofs; int* glcol;
  u16* w1f; u16* w2f0; u16* w2f1; u16* w2f2; u16* w1nf1; u16* w1nf2;
  u16* zA; u16* zB; float* gsum; float* gmax; int* gcnt;
};

// S layouts:
//  bingemm (41472): bin: staged@0 stb@16384 hist@24576 lofs@27712
//                   lcur@30848 gbase@33984 sd@37120 | gemm: w1h@0 Xt@16384
//  agg/aggcsr (27648): lcol/H2@0(9216) H1/w1nh@9216(9216) w2h@18432(8192)
//                      b2s@26624(256) lofs@26880(260) bt@27144(256)
//                      csr scratch (aggcsr only): lhist@9216 lcur@9472
//                      ssc@9728 (aliases dead H1 region)
//  head (18432): gs@0

__device__ __forceinline__ int lb_dev(const int* __restrict__ a, int n, int v) {
  int lo = 0, hi = n;
  while (lo < hi) {
    int m = (lo + hi) >> 1;
    if (a[m] < v) lo = m + 1; else hi = m;
  }
  return lo;
}

__device__ __forceinline__ void setup_body(const GinParams& p, int vb) {
  const int tid = threadIdx.x;
  if (vb == 0) {  // w1: 128x64 swizzle
    for (int i = tid; i < 8192; i += NTHR) {
      int jj = i & 7, lane = (i >> 3) & 63, c = i >> 9;
      int nt = c >> 2, ks = c & 3;
      int mrow = lane & 15, quad = lane >> 4;
      p.w1f[i] = f2b(p.w1g[(ks * 32 + quad * 8 + jj) * 64 + nt * 16 + mrow]);
    }
  } else if (vb < 6) {  // 64x64 weights
    const float* s = (vb == 1) ? p.w2a : (vb == 2) ? p.w2b
                     : (vb == 3) ? p.w2c : (vb == 4) ? p.w1b : p.w1c;
    u16* d = (vb == 1) ? p.w2f0 : (vb == 2) ? p.w2f1
             : (vb == 3) ? p.w2f2 : (vb == 4) ? p.w1nf1 : p.w1nf2;
    for (int i = tid; i < 4096; i += NTHR) {
      int jj = i & 7, lane = (i >> 3) & 63, c = i >> 9;
      int nt = c >> 1, ks = c & 1;
      int mrow = lane & 15, quad = lane >> 4;
      d[i] = f2b(s[(ks * 32 + quad * 8 + jj) * 64 + nt * 16 + mrow]);
    }
  } else if (vb == 6) {  // gcur zero + sentinel rows
    for (int i = tid; i < NB; i += NTHR) p.gcur[i] = 0;
    if (tid < 64) p.zA[(size_t)NNODES * 64 + tid] = 0;
    else if (tid < 128) p.zB[(size_t)NNODES * 64 + (tid - 64)] = 0;
  } else if (vb == 7) {  // per-graph node counts
    for (int g = tid; g < NGRAPHS; g += NTHR)
      p.gcnt[g] = lb_dev(p.batch, NNODES, g + 1) - lb_dev(p.batch, NNODES, g);
  } else {  // zero gsum||gmax: 96 vblocks x 512 x 16B = 2x393216B
    ((int4*)p.gsum)[(vb - 8) * NTHR + tid] = make_int4(0, 0, 0, 0);
  }
}

__device__ __forceinline__ void bin_body(const GinParams& p, char* S, int cb) {
  int* staged = (int*)S;
  u16* stb = (u16*)(S + 16384);
  int* hist = (int*)(S + 24576);
  int* lofs = (int*)(S + 27712);
  int* lcur = (int*)(S + 30848);
  int* gbase = (int*)(S + 33984);
  int* sd = (int*)(S + 37120);
  const int t = threadIdx.x;
  const int e0 = cb * CHUNK;
  const int n = min(CHUNK, NEDGES - e0);

  for (int i = t; i < NB; i += NTHR) hist[i] = 0;
  __syncthreads();

  int pk[8];
  int bk[8];
#pragma unroll
  for (int k = 0; k < 8; ++k) {
    int i = t + k * NTHR;
    if (i < n) {
      int s = p.src[e0 + i];
      int d = p.dst[e0 + i];
      int b = d >> 7;
      pk[k] = (s << 7) | (d & 127);
      bk[k] = b;
      atomicAdd(&hist[b], 1);
    } else {
      bk[k] = -1;
    }
  }
  __syncthreads();

  sd[t] = (t < NB) ? hist[t] : 0;
  sd[t + 512] = (t + 512 < NB) ? hist[t + 512] : 0;
  __syncthreads();
  for (int off = 1; off < 1024; off <<= 1) {
    int v0 = (t >= off) ? sd[t - off] : 0;
    int v1 = (t + 512 >= off) ? sd[t + 512 - off] : 0;
    __syncthreads();
    sd[t] += v0;
    sd[t + 512] += v1;
    __syncthreads();
  }
  if (t == 0) lofs[0] = 0;
  for (int i = t; i < NB; i += NTHR) {
    int inc = sd[i];
    int c = hist[i];
    lofs[i + 1] = inc;
    lcur[i] = inc - c;
    gbase[i] = c ? atomicAdd(&p.gcur[i], c) : 0;  // zero-based cursor
  }
  __syncthreads();

#pragma unroll
  for (int k = 0; k < 8; ++k) {
    if (bk[k] >= 0) {
      int r = atomicAdd(&lcur[bk[k]], 1);
      staged[r] = pk[k];
      stb[r] = (u16)bk[k];
    }
  }
  __syncthreads();

  for (int i = t; i < n; i += NTHR) {
    int b = stb[i];
    p.st[(size_t)b * BCAP + gbase[b] + (i - lofs[b])] = staged[i];
  }
}

__device__ __forceinline__ void gemm_body(const GinParams& p, char* S,
                                          int tile) {
  u16* w1h = (u16*)S;
  u16* Xt = (u16*)(S + 16384);
  const int tid = threadIdx.x;
  const int base = tile * 64;
  for (int i = tid; i < 1024; i += NTHR)
    ((int4*)w1h)[i] = ((const int4*)p.w1f)[i];
  for (int i = tid; i < 2048; i += NTHR) {
    int n = i >> 5, c4 = i & 31;
    int nn = base + n;
    float4 v = make_float4(0.f, 0.f, 0.f, 0.f);
    if (nn < NNODES) v = *(const float4*)&p.x[(size_t)nn * 128 + 4 * c4];
    u32 p0 = (u32)f2b(v.x) | ((u32)f2b(v.y) << 16);
    u32 p1 = (u32)f2b(v.z) | ((u32)f2b(v.w) << 16);
    *(u32*)&Xt[n * XSTR + 4 * c4] = p0;
    *(u32*)&Xt[n * XSTR + 4 * c4 + 2] = p1;
  }
  __syncthreads();
  const int lane = tid & 63;
  const int wv = tid >> 6;
  const int mrow = lane & 15;
  const int quad = lane >> 4;
  f32x4 accs[4];
  if (wv < 4) {
#pragma unroll
    for (int nt = 0; nt < 4; ++nt) {
      f32x4 acc = {0.f, 0.f, 0.f, 0.f};
#pragma unroll
      for (int ks = 0; ks < 4; ++ks) {
        short8 afr =
            *(const short8*)&Xt[(wv * 16 + mrow) * XSTR + ks * 32 + quad * 8];
        short8 bfr = *(const short8*)&w1h[((nt * 4 + ks) * 64 + lane) * 8];
        acc = __builtin_amdgcn_mfma_f32_16x16x32_bf16(afr, bfr, acc, 0, 0, 0);
      }
      accs[nt] = acc;
    }
  }
  __syncthreads();
  u16* Zt = Xt;
  if (wv < 4) {
#pragma unroll
    for (int nt = 0; nt < 4; ++nt)
#pragma unroll
      for (int r = 0; r < 4; ++r)
        Zt[(wv * 16 + quad * 4 + r) * HSTR + nt * 16 + mrow] =
            f2b(accs[nt][r]);
  }
  __syncthreads();
  for (int i = tid; i < 2048; i += NTHR) {
    int n = i >> 5, kk = i & 31;
    int nn = base + n;
    if (nn < NNODES)
      *(u32*)&p.zA[(size_t)nn * 64 + 2 * kk] = *(u32*)&Zt[n * HSTR + 2 * kk];
  }
}

// PRE=true: lcol (S@0) and lofs (S+26880, clamped) already built in LDS.
// Caller must have staged w2h (S+18432) and b2s (S+26624).
template <bool PRE>
__device__ __forceinline__ void agg_body(const GinParams& p, char* S, int blk,
                                         int li, const u16* zin, u16* zn,
                                         const float* b1p, const u16* w1nf,
                                         bool hasnext) {
  int* lcol = (int*)S;
  u16* H2 = (u16*)S;
  u16* H1 = (u16*)(S + 9216);
  u16* w1nh = (u16*)(S + 9216);
  u16* w2h = (u16*)(S + 18432);
  float* b2s = (float*)(S + 26624);
  int* lofs = (int*)(S + 26880);
  int* bt = (int*)(S + 27144);
  const int tid = threadIdx.x;
  const int lane = tid & 63;
  const int wv = tid >> 6;
  const int sub = lane >> 5;
  const int fl = lane & 31;
  const int f = 2 * fl + sub;
  const int base = blk << 6;

  if (tid < 64) {
    int nn = base + tid;
    bt[tid] = (nn < NNODES) ? p.batch[nn] : -1;
  }
  if (!PRE) {
    if (tid < 65) lofs[tid] = p.glofs[blk * GOFS + tid];
  }
  __syncthreads();
  if (!PRE) {
    const int L = lofs[64];
    int4* ldst = (int4*)lcol;
    const int4* gsrc = (const int4*)(p.glcol + (size_t)blk * LCAP);
    for (int i = tid; i < (L >> 2); i += NTHR) ldst[i] = gsrc[i];
    __syncthreads();
  }

  const float e1 = 1.0f + p.eps[li];
  const float b1v = b1p[f];
  const int n0g = wv * 8;

#pragma unroll 1
  for (int j = 0; j < 8; ++j) {
    int ln = n0g + j;
    int nn = base + ln;
    int sn = (nn < NNODES) ? nn : NNODES;
    int rs = lofs[ln], re = lofs[ln + 1];
    float sa0 = 0.f, sa1 = 0.f, sa2 = 0.f, sa3 = 0.f;
    float sb0 = 0.f, sb1 = 0.f, sb2 = 0.f, sb3 = 0.f;
    for (int e = rs; e < re; e += 16) {
      int c0 = lcol[e + 0 + sub];
      int c1 = lcol[e + 2 + sub];
      int c2 = lcol[e + 4 + sub];
      int c3 = lcol[e + 6 + sub];
      int c4 = lcol[e + 8 + sub];
      int c5 = lcol[e + 10 + sub];
      int c6 = lcol[e + 12 + sub];
      int c7 = lcol[e + 14 + sub];
      u32 v0 = *(const u32*)&zin[(size_t)c0 * 64 + 2 * fl];
      u32 v1 = *(const u32*)&zin[(size_t)c1 * 64 + 2 * fl];
      u32 v2 = *(const u32*)&zin[(size_t)c2 * 64 + 2 * fl];
      u32 v3 = *(const u32*)&zin[(size_t)c3 * 64 + 2 * fl];
      u32 v4 = *(const u32*)&zin[(size_t)c4 * 64 + 2 * fl];
      u32 v5 = *(const u32*)&zin[(size_t)c5 * 64 + 2 * fl];
      u32 v6 = *(const u32*)&zin[(size_t)c6 * 64 + 2 * fl];
      u32 v7 = *(const u32*)&zin[(size_t)c7 * 64 + 2 * fl];
      sa0 += __uint_as_float(v0 << 16);
      sb0 += __uint_as_float(v0 & 0xffff0000u);
      sa1 += __uint_as_float(v1 << 16);
      sb1 += __uint_as_float(v1 & 0xffff0000u);
      sa2 += __uint_as_float(v2 << 16);
      sb2 += __uint_as_float(v2 & 0xffff0000u);
      sa3 += __uint_as_float(v3 << 16);
      sb3 += __uint_as_float(v3 & 0xffff0000u);
      sa0 += __uint_as_float(v4 << 16);
      sb0 += __uint_as_float(v4 & 0xffff0000u);
      sa1 += __uint_as_float(v5 << 16);
      sb1 += __uint_as_float(v5 & 0xffff0000u);
      sa2 += __uint_as_float(v6 << 16);
      sb2 += __uint_as_float(v6 & 0xffff0000u);
      sa3 += __uint_as_float(v7 << 16);
      sb3 += __uint_as_float(v7 & 0xffff0000u);
    }
    float sa = (sa0 + sa1) + (sa2 + sa3);
    float sb = (sb0 + sb1) + (sb2 + sb3);
    sa += __shfl_xor(sa, 32);
    sb += __shfl_xor(sb, 32);
    float sum = sub ? sb : sa;
    float self = b2f(zin[(size_t)sn * 64 + f]);
    float h = fmaxf(sum + e1 * self + b1v, 0.f);
    H1[ln * HSTR + f] = f2b(h);
  }
  __syncthreads();  // lcol reads done block-wide; H1 fully written

  const int mrow = lane & 15;
  const int quad = lane >> 4;
  if (wv < 4) {
    f32x4 m1[4];
#pragma unroll
    for (int nt = 0; nt < 4; ++nt) {
      f32x4 acc = {0.f, 0.f, 0.f, 0.f};
#pragma unroll
      for (int ks = 0; ks < 2; ++ks) {
        short8 afr =
            *(const short8*)&H1[(wv * 16 + mrow) * HSTR + ks * 32 + quad * 8];
        short8 bfr = *(const short8*)&w2h[((nt * 2 + ks) * 64 + lane) * 8];
        acc = __builtin_amdgcn_mfma_f32_16x16x32_bf16(afr, bfr, acc, 0, 0, 0);
      }
      m1[nt] = acc;
    }
    LDS_FENCE();
#pragma unroll
    for (int nt = 0; nt < 4; ++nt) {
      float bb = b2s[nt * 16 + mrow];
#pragma unroll
      for (int r = 0; r < 4; ++r)
        H2[(wv * 16 + quad * 4 + r) * HSTR + nt * 16 + mrow] =
            f2b(fmaxf(m1[nt][r] + bb, 0.f));
    }
  }
  __syncthreads();  // H2 visible to all waves for pooling

  {
    const int n0p = wv * 8;
    float s = 0.f, m = 0.f;
    int cur = bt[n0p];
#pragma unroll 1
    for (int j = 0; j < 8; ++j) {
      int b = bt[n0p + j];
      if (b != cur) {
        if (cur >= 0) {
          atomicAdd(&p.gsum[cur * 192 + li * 64 + lane], s);
          atomicMax((u32*)&p.gmax[cur * 192 + li * 64 + lane],
                    __float_as_uint(m));
        }
        s = 0.f;
        m = 0.f;
        cur = b;
      }
      if (b >= 0) {
        float v = b2f(H2[(n0p + j) * HSTR + lane]);
        s += v;
        m = fmaxf(m, v);
      }
    }
    if (cur >= 0) {
      atomicAdd(&p.gsum[cur * 192 + li * 64 + lane], s);
      atomicMax((u32*)&p.gmax[cur * 192 + li * 64 + lane],
                __float_as_uint(m));
    }
  }

  if (hasnext) {
    __syncthreads();  // pooling reads of H2 done; H1 fully dead
    for (int i = tid; i < 512; i += NTHR)
      ((int4*)w1nh)[i] = ((const int4*)w1nf)[i];
    __syncthreads();
    if (wv < 4) {
      f32x4 m2[4];
#pragma unroll
      for (int nt = 0; nt < 4; ++nt) {
        f32x4 acc = {0.f, 0.f, 0.f, 0.f};
#pragma unroll
        for (int ks = 0; ks < 2; ++ks) {
          short8 afr =
              *(const short8*)&H2[(wv * 16 + mrow) * HSTR + ks * 32 + quad * 8];
          short8 bfr = *(const short8*)&w1nh[((nt * 2 + ks) * 64 + lane) * 8];
          acc = __builtin_amdgcn_mfma_f32_16x16x32_bf16(afr, bfr, acc, 0, 0, 0);
        }
        m2[nt] = acc;
      }
      LDS_FENCE();
#pragma unroll
      for (int nt = 0; nt < 4; ++nt)
#pragma unroll
        for (int r = 0; r < 4; ++r)
          H2[(wv * 16 + quad * 4 + r) * HSTR + nt * 16 + mrow] =
              f2b(m2[nt][r]);
    }
    __syncthreads();
    for (int i = tid; i < 2048; i += NTHR) {
      int n = i >> 5, kk = i & 31;
      int nn = base + n;
      if (nn < NNODES)
        *(u32*)&zn[(size_t)nn * 64 + 2 * kk] = *(u32*)&H2[n * HSTR + 2 * kk];
    }
  }
}

__device__ __forceinline__ void head_body(const GinParams& p, char* S,
                                          int vb) {
  float* gs = (float*)S;  // 8*576 floats = 18432 B
  const int tid = threadIdx.x;
  int g0 = vb * 8;
  for (int i = tid; i < 8 * 192; i += NTHR) {
    int w = i / 192, idx = i - w * 192;
    int gi = g0 + w;
    float Sv = p.gsum[gi * 192 + idx];
    float M = p.gmax[gi * 192 + idx];
    float C = (float)p.gcnt[gi];
    gs[w * 576 + idx] = Sv / fmaxf(C, 1.0f);
    gs[w * 576 + 192 + idx] = M;
    gs[w * 576 + 384 + idx] = Sv;
  }
  __syncthreads();
  int wv = tid >> 6, lane = tid & 63;
  int gi = g0 + wv;
  const float* grow = &gs[wv * 576];
  float acc = p.fc1b[lane];
#pragma unroll 8
  for (int k = 0; k < 576; ++k) acc += grow[k] * p.fc1w[k * 64 + lane];
  acc = fmaxf(acc, 0.f);
  float p0 = acc * p.fc2w[lane * 2 + 0];
  float p1 = acc * p.fc2w[lane * 2 + 1];
  for (int off = 32; off; off >>= 1) {
    p0 += __shfl_down(p0, off);
    p1 += __shfl_down(p1, off);
  }
  if (lane == 0) {
    p.out[gi * 2 + 0] = 1.f / (1.f + __expf(-(p0 + p.fc2b[0])));
    p.out[gi * 2 + 1] = 1.f / (1.f + __expf(-(p1 + p.fc2b[1])));
  }
}

// ---------------- kernels ----------------

__global__ __launch_bounds__(NTHR) void setup_kernel(GinParams p) {
  setup_body(p, blockIdx.x);
}

// bin (blocks 0..NCHUNKS-1) || gemm (blocks NCHUNKS..): independent outputs
__global__ __launch_bounds__(NTHR) void bingemm_kernel(GinParams p) {
  __shared__ __align__(16) char S[41472];
  if (blockIdx.x < NCHUNKS)
    bin_body(p, S, blockIdx.x);
  else
    gemm_body(p, S, blockIdx.x - NCHUNKS);
}

// csr + agg layer 0 fused: build lcol/lofs in LDS, persist glofs/glcol for
// layers 1-2, then gather straight from the LDS copy.
__global__ __launch_bounds__(NTHR, 8) void aggcsr_kernel(GinParams p) {
  __shared__ __align__(16) char S[27648];
  const int tid = threadIdx.x;
  const int blk = blockIdx.x;
  int* lcol = (int*)S;
  int* lhist = (int*)(S + 9216);   // aliases H1 region (dead during csr)
  int* lcur = (int*)(S + 9472);
  int* ssc = (int*)(S + 9728);
  u16* w2h = (u16*)(S + 18432);
  float* b2s = (float*)(S + 26624);
  int* lofs = (int*)(S + 26880);   // agg's lofs; csr writes it clamped

  // stage w2h/b2s for layer 0 (regions disjoint from csr scratch)
  for (int i = tid; i < 512; i += NTHR)
    ((int4*)w2h)[i] = ((const int4*)p.w2f0)[i];
  if (tid < 64) b2s[tid] = p.b2_0[tid];

  const int bkt = blk >> 1;
  const int half = blk & 1;
  const int ofs = bkt * BCAP;
  const int cnt = min(p.gcur[bkt], BCAP);

  if (tid < 64) lhist[tid] = 0;
  __syncthreads();
  for (int i = tid; i < cnt; i += NTHR) {
    int d7 = p.st[ofs + i] & 127;
    if ((d7 >> 6) == half) atomicAdd(&lhist[d7 & 63], 1);
  }
  __syncthreads();
  if (tid < 64) ssc[tid] = (lhist[tid] + 15) & ~15;
  __syncthreads();
  for (int off = 1; off < 64; off <<= 1) {
    int v = (tid < 64 && tid >= off) ? ssc[tid - off] : 0;
    __syncthreads();
    if (tid < 64) ssc[tid] += v;
    __syncthreads();
  }
  if (tid < 64) {
    lofs[tid + 1] = min(ssc[tid], LCAP);
    lcur[tid] = ssc[tid] - ((lhist[tid] + 15) & ~15);
  }
  if (tid == 0) lofs[0] = 0;
  __syncthreads();
  for (int i = tid; i < cnt; i += NTHR) {
    int pkt = p.st[ofs + i];
    int d7 = pkt & 127;
    if ((d7 >> 6) == half) {
      int r = atomicAdd(&lcur[d7 & 63], 1);
      if (r < LCAP) lcol[r] = pkt >> 7;
    }
  }
  __syncthreads();
  if (tid < 64) {
    int re = lofs[tid + 1];  // already clamped
    for (int r = lcur[tid]; r < re; ++r) lcol[r] = NNODES;
  }
  __syncthreads();
  // persist CSR for layers 1-2
  if (tid < 65) p.glofs[blk * GOFS + tid] = lofs[tid];
  {
    int L = lofs[64];
    int4* gdst = (int4*)(p.glcol + (size_t)blk * LCAP);
    const int4* lsrc = (const int4*)lcol;
    for (int i = tid; i < (L >> 2); i += NTHR) gdst[i] = lsrc[i];
  }
  // agg layer 0 straight from LDS lcol/lofs (PRE=true)
  agg_body<true>(p, S, blk, 0, p.zA, p.zB, p.b1_0, p.w1nf1, true);
}

template <bool HN>
__global__ __launch_bounds__(NTHR, 8) void agg_kernel(GinParams p, int li,
                                                      const u16* zin, u16* zn,
                                                      const float* b1p,
                                                      const u16* w1nf,
                                                      const u16* w2f,
                                                      const float* b2p) {
  __shared__ __align__(16) char S[27648];
  u16* w2h = (u16*)(S + 18432);
  float* b2s = (float*)(S + 26624);
  for (int i = threadIdx.x; i < 512; i += NTHR)
    ((int4*)w2h)[i] = ((const int4*)w2f)[i];
  if (threadIdx.x < 64) b2s[threadIdx.x] = b2p[threadIdx.x];
  __syncthreads();
  agg_body<false>(p, S, blockIdx.x, li, zin, zn, b1p, w1nf, HN);
}

__global__ __launch_bounds__(NTHR) void head_kernel(GinParams p) {
  __shared__ __align__(16) char S[18432];
  head_body(p, S, blockIdx.x);
}

// ---------------- launch ----------------

extern "C" void kernel_launch(void* const* d_in, const int* in_sizes, int n_in,
                              void* d_out, int out_size, void* d_ws,
                              size_t ws_size, hipStream_t stream) {
  const float* x = (const float*)d_in[0];
  const int* ei = (const int*)d_in[1];
  const int* src = ei;
  const int* dst = ei + NEDGES;
  const int* batch = (const int*)d_in[2];
  const float* lw1[3] = {(const float*)d_in[3], (const float*)d_in[7],
                         (const float*)d_in[11]};
  const float* lb1[3] = {(const float*)d_in[4], (const float*)d_in[8],
                         (const float*)d_in[12]};
  const float* lw2[3] = {(const float*)d_in[5], (const float*)d_in[9],
                         (const float*)d_in[13]};
  const float* lb2[3] = {(const float*)d_in[6], (const float*)d_in[10],
                         (const float*)d_in[14]};
  const float* eps = (const float*)d_in[15];
  const float* fc1w = (const float*)d_in[16];
  const float* fc1b = (const float*)d_in[17];
  const float* fc2w = (const float*)d_in[18];
  const float* fc2b = (const float*)d_in[19];
  float* out = (float*)d_out;

  char* p = (char*)d_ws;
  auto carve = [&](size_t bytes) {
    void* r = (void*)p;
    p += (bytes + 1023) & ~(size_t)1023;
    return r;
  };
  float* gsum = (float*)carve((size_t)NGRAPHS * 192 * 4);
  float* gmax = (float*)carve((size_t)NGRAPHS * 192 * 4);
  int* gcur = (int*)carve((NB + 4) * 4);
  int* st = (int*)carve((size_t)NB * BCAP * 4);
  int* glofs = (int*)carve((size_t)NBH * GOFS * 4);
  int* glcol = (int*)carve((size_t)NBH * LCAP * 4);
  u16* w1f = (u16*)carve(8192 * 2);
  u16* w2f0 = (u16*)carve(4096 * 2);
  u16* w2f1 = (u16*)carve(4096 * 2);
  u16* w2f2 = (u16*)carve(4096 * 2);
  u16* w1nf1 = (u16*)carve(4096 * 2);
  u16* w1nf2 = (u16*)carve(4096 * 2);
  u16* zA = (u16*)carve((size_t)(NNODES + 1) * 64 * 2);
  u16* zB = (u16*)carve((size_t)(NNODES + 1) * 64 * 2);
  int* gcnt = (int*)carve(NGRAPHS * 4);

  GinParams prm;
  prm.src = src; prm.dst = dst; prm.batch = batch; prm.x = x;
  prm.w1g = lw1[0]; prm.w2a = lw2[0]; prm.w2b = lw2[1]; prm.w2c = lw2[2];
  prm.w1b = lw1[1]; prm.w1c = lw1[2];
  prm.b1_0 = lb1[0]; prm.b1_1 = lb1[1]; prm.b1_2 = lb1[2];
  prm.b2_0 = lb2[0]; prm.b2_1 = lb2[1]; prm.b2_2 = lb2[2];
  prm.eps = eps;
  prm.fc1w = fc1w; prm.fc1b = fc1b; prm.fc2w = fc2w; prm.fc2b = fc2b;
  prm.out = out;
  prm.gcur = gcur; prm.st = st; prm.glofs = glofs; prm.glcol = glcol;
  prm.w1f = w1f; prm.w2f0 = w2f0; prm.w2f1 = w2f1; prm.w2f2 = w2f2;
  prm.w1nf1 = w1nf1; prm.w1nf2 = w1nf2;
  prm.zA = zA; prm.zB = zB; prm.gsum = gsum; prm.gmax = gmax; prm.gcnt = gcnt;

  setup_kernel<<<NSETUP, NTHR, 0, stream>>>(prm);
  bingemm_kernel<<<NCHUNKS + NGEMM, NTHR, 0, stream>>>(prm);
  aggcsr_kernel<<<NBH, NTHR, 0, stream>>>(prm);
  agg_kernel<true><<<NBH, NTHR, 0, stream>>>(prm, 1, zB, zA, lb1[1], w1nf2,
                                             w2f1, lb2[1]);
  agg_kernel<false><<<NBH, NTHR, 0, stream>>>(prm, 2, zA, (u16*)nullptr,
                                              lb1[2], w1nf2, w2f2, lb2[2]);
  head_kernel<<<NGRAPHS / 8, NTHR, 0, stream>>>(prm);
}

// Round 10
// 307.131 us; speedup vs baseline: 1.0606x; 1.0016x over previous
//
#include <hip/hip_runtime.h>
#include <math.h>

// GIN v16: dependency-split setup. v15 (307.6us) showed fusion along true
// block-dependencies works (aggcsr 57.3 vs 64.5+gap). Remaining provable
// waste: setup (104 blocks) sits on the critical path but only w1f (gemm)
// and gcur (bin) are needed by dispatch 2. v16: setup shrinks to 2 blocks;
// the other 102 (agg-weight swizzles, gcnt, sentinels, 96 gsum/gmax-zero
// blocks) become bingemm tail extras - consumed from dispatch 3 onward,
// hidden under bin's long blocks. All other kernels byte-identical to v15.

#define NNODES 100000
#define NEDGES 1600000
#define NGRAPHS 512
#define NB 782
#define NBH 1564
#define BCAP 2560
#define LCAP 2304
#define GOFS 72
#define CHUNK 4096
#define NCHUNKS 391
#define NGEMM 1563
#define NEXTRA 103
#define HSTR 72   // H1/H2 row stride (u16): 144B
#define XSTR 136  // gemm x-tile row stride (u16)
#define NTHR 512

typedef unsigned short u16;
typedef unsigned int u32;
typedef __attribute__((ext_vector_type(8))) short short8;
typedef __attribute__((ext_vector_type(4))) float f32x4;

__device__ __forceinline__ u16 f2b(float f) {
  union { float f; unsigned u; } v;
  v.f = f;
  unsigned r = v.u + 0x7FFF + ((v.u >> 16) & 1);
  return (u16)(r >> 16);
}
__device__ __forceinline__ float b2f(u16 h) {
  union { unsigned u; float f; } v;
  v.u = ((unsigned)h) << 16;
  return v.f;
}
#define LDS_FENCE() __asm__ volatile("s_waitcnt lgkmcnt(0)" ::: "memory")

struct GinParams {
  const int* src; const int* dst; const int* batch; const float* x;
  const float* w1g; const float* w2a; const float* w2b; const float* w2c;
  const float* w1b; const float* w1c;
  const float* b1_0; const float* b1_1; const float* b1_2;
  const float* b2_0; const float* b2_1; const float* b2_2;
  const float* eps;
  const float* fc1w; const float* fc1b; const float* fc2w; const float* fc2b;
  float* out;
  int* gcur; int* st; int* glofs; int* glcol;
  u16* w1f; u16* w2f0; u16* w2f1; u16* w2f2; u16* w1nf1; u16* w1nf2;
  u16* zA; u16* zB; float* gsum; float* gmax; int* gcnt;
};

__device__ __forceinline__ int lb_dev(const int* __restrict__ a, int n, int v) {
  int lo = 0, hi = n;
  while (lo < hi) {
    int m = (lo + hi) >> 1;
    if (a[m] < v) lo = m + 1; else hi = m;
  }
  return lo;
}

// 64x64 weight swizzle to MFMA B-fragment order
__device__ __forceinline__ void wswz64(const float* __restrict__ s,
                                       u16* __restrict__ d) {
  for (int i = threadIdx.x; i < 4096; i += NTHR) {
    int jj = i & 7, lane = (i >> 3) & 63, c = i >> 9;
    int nt = c >> 1, ks = c & 1;
    int mrow = lane & 15, quad = lane >> 4;
    d[i] = f2b(s[(ks * 32 + quad * 8 + jj) * 64 + nt * 16 + mrow]);
  }
}

// extras riding in bingemm's tail: consumed from dispatch 3 onward
__device__ __forceinline__ void extra_body(const GinParams& p, int vb) {
  const int tid = threadIdx.x;
  if (vb == 0) wswz64(p.w2a, p.w2f0);
  else if (vb == 1) wswz64(p.w2b, p.w2f1);
  else if (vb == 2) wswz64(p.w2c, p.w2f2);
  else if (vb == 3) wswz64(p.w1b, p.w1nf1);
  else if (vb == 4) wswz64(p.w1c, p.w1nf2);
  else if (vb == 5) {  // per-graph node counts (consumed by head)
    for (int g = tid; g < NGRAPHS; g += NTHR)
      p.gcnt[g] = lb_dev(p.batch, NNODES, g + 1) - lb_dev(p.batch, NNODES, g);
  } else if (vb == 6) {  // sentinel rows (consumed by agg gathers)
    if (tid < 64) p.zA[(size_t)NNODES * 64 + tid] = 0;
    else if (tid < 128) p.zB[(size_t)NNODES * 64 + (tid - 64)] = 0;
  } else {  // zero gsum||gmax: 96 vblocks x 512 x 16B = 2x393216B
    ((int4*)p.gsum)[(vb - 7) * NTHR + tid] = make_int4(0, 0, 0, 0);
  }
}

__device__ __forceinline__ void bin_body(const GinParams& p, char* S, int cb) {
  int* staged = (int*)S;
  u16* stb = (u16*)(S + 16384);
  int* hist = (int*)(S + 24576);
  int* lofs = (int*)(S + 27712);
  int* lcur = (int*)(S + 30848);
  int* gbase = (int*)(S + 33984);
  int* sd = (int*)(S + 37120);
  const int t = threadIdx.x;
  const int e0 = cb * CHUNK;
  const int n = min(CHUNK, NEDGES - e0);

  for (int i = t; i < NB; i += NTHR) hist[i] = 0;
  __syncthreads();

  int pk[8];
  int bk[8];
#pragma unroll
  for (int k = 0; k < 8; ++k) {
    int i = t + k * NTHR;
    if (i < n) {
      int s = p.src[e0 + i];
      int d = p.dst[e0 + i];
      int b = d >> 7;
      pk[k] = (s << 7) | (d & 127);
      bk[k] = b;
      atomicAdd(&hist[b], 1);
    } else {
      bk[k] = -1;
    }
  }
  __syncthreads();

  sd[t] = (t < NB) ? hist[t] : 0;
  sd[t + 512] = (t + 512 < NB) ? hist[t + 512] : 0;
  __syncthreads();
  for (int off = 1; off < 1024; off <<= 1) {
    int v0 = (t >= off) ? sd[t - off] : 0;
    int v1 = (t + 512 >= off) ? sd[t + 512 - off] : 0;
    __syncthreads();
    sd[t] += v0;
    sd[t + 512] += v1;
    __syncthreads();
  }
  if (t == 0) lofs[0] = 0;
  for (int i = t; i < NB; i += NTHR) {
    int inc = sd[i];
    int c = hist[i];
    lofs[i + 1] = inc;
    lcur[i] = inc - c;
    gbase[i] = c ? atomicAdd(&p.gcur[i], c) : 0;  // zero-based cursor
  }
  __syncthreads();

#pragma unroll
  for (int k = 0; k < 8; ++k) {
    if (bk[k] >= 0) {
      int r = atomicAdd(&lcur[bk[k]], 1);
      staged[r] = pk[k];
      stb[r] = (u16)bk[k];
    }
  }
  __syncthreads();

  for (int i = t; i < n; i += NTHR) {
    int b = stb[i];
    p.st[(size_t)b * BCAP + gbase[b] + (i - lofs[b])] = staged[i];
  }
}

__device__ __forceinline__ void gemm_body(const GinParams& p, char* S,
                                          int tile) {
  u16* w1h = (u16*)S;
  u16* Xt = (u16*)(S + 16384);
  const int tid = threadIdx.x;
  const int base = tile * 64;
  for (int i = tid; i < 1024; i += NTHR)
    ((int4*)w1h)[i] = ((const int4*)p.w1f)[i];
  for (int i = tid; i < 2048; i += NTHR) {
    int n = i >> 5, c4 = i & 31;
    int nn = base + n;
    float4 v = make_float4(0.f, 0.f, 0.f, 0.f);
    if (nn < NNODES) v = *(const float4*)&p.x[(size_t)nn * 128 + 4 * c4];
    u32 p0 = (u32)f2b(v.x) | ((u32)f2b(v.y) << 16);
    u32 p1 = (u32)f2b(v.z) | ((u32)f2b(v.w) << 16);
    *(u32*)&Xt[n * XSTR + 4 * c4] = p0;
    *(u32*)&Xt[n * XSTR + 4 * c4 + 2] = p1;
  }
  __syncthreads();
  const int lane = tid & 63;
  const int wv = tid >> 6;
  const int mrow = lane & 15;
  const int quad = lane >> 4;
  f32x4 accs[4];
  if (wv < 4) {
#pragma unroll
    for (int nt = 0; nt < 4; ++nt) {
      f32x4 acc = {0.f, 0.f, 0.f, 0.f};
#pragma unroll
      for (int ks = 0; ks < 4; ++ks) {
        short8 afr =
            *(const short8*)&Xt[(wv * 16 + mrow) * XSTR + ks * 32 + quad * 8];
        short8 bfr = *(const short8*)&w1h[((nt * 4 + ks) * 64 + lane) * 8];
        acc = __builtin_amdgcn_mfma_f32_16x16x32_bf16(afr, bfr, acc, 0, 0, 0);
      }
      accs[nt] = acc;
    }
  }
  __syncthreads();
  u16* Zt = Xt;
  if (wv < 4) {
#pragma unroll
    for (int nt = 0; nt < 4; ++nt)
#pragma unroll
      for (int r = 0; r < 4; ++r)
        Zt[(wv * 16 + quad * 4 + r) * HSTR + nt * 16 + mrow] =
            f2b(accs[nt][r]);
  }
  __syncthreads();
  for (int i = tid; i < 2048; i += NTHR) {
    int n = i >> 5, kk = i & 31;
    int nn = base + n;
    if (nn < NNODES)
      *(u32*)&p.zA[(size_t)nn * 64 + 2 * kk] = *(u32*)&Zt[n * HSTR + 2 * kk];
  }
}

// PRE=true: lcol (S@0) and lofs (S+26880, clamped) already built in LDS.
// Caller must have staged w2h (S+18432) and b2s (S+26624).
template <bool PRE>
__device__ __forceinline__ void agg_body(const GinParams& p, char* S, int blk,
                                         int li, const u16* zin, u16* zn,
                                         const float* b1p, const u16* w1nf,
                                         bool hasnext) {
  int* lcol = (int*)S;
  u16* H2 = (u16*)S;
  u16* H1 = (u16*)(S + 9216);
  u16* w1nh = (u16*)(S + 9216);
  u16* w2h = (u16*)(S + 18432);
  float* b2s = (float*)(S + 26624);
  int* lofs = (int*)(S + 26880);
  int* bt = (int*)(S + 27144);
  const int tid = threadIdx.x;
  const int lane = tid & 63;
  const int wv = tid >> 6;
  const int sub = lane >> 5;
  const int fl = lane & 31;
  const int f = 2 * fl + sub;
  const int base = blk << 6;

  if (tid < 64) {
    int nn = base + tid;
    bt[tid] = (nn < NNODES) ? p.batch[nn] : -1;
  }
  if (!PRE) {
    if (tid < 65) lofs[tid] = p.glofs[blk * GOFS + tid];
  }
  __syncthreads();
  if (!PRE) {
    const int L = lofs[64];
    int4* ldst = (int4*)lcol;
    const int4* gsrc = (const int4*)(p.glcol + (size_t)blk * LCAP);
    for (int i = tid; i < (L >> 2); i += NTHR) ldst[i] = gsrc[i];
    __syncthreads();
  }

  const float e1 = 1.0f + p.eps[li];
  const float b1v = b1p[f];
  const int n0g = wv * 8;

#pragma unroll 1
  for (int j = 0; j < 8; ++j) {
    int ln = n0g + j;
    int nn = base + ln;
    int sn = (nn < NNODES) ? nn : NNODES;
    int rs = lofs[ln], re = lofs[ln + 1];
    float sa0 = 0.f, sa1 = 0.f, sa2 = 0.f, sa3 = 0.f;
    float sb0 = 0.f, sb1 = 0.f, sb2 = 0.f, sb3 = 0.f;
    for (int e = rs; e < re; e += 16) {
      int c0 = lcol[e + 0 + sub];
      int c1 = lcol[e + 2 + sub];
      int c2 = lcol[e + 4 + sub];
      int c3 = lcol[e + 6 + sub];
      int c4 = lcol[e + 8 + sub];
      int c5 = lcol[e + 10 + sub];
      int c6 = lcol[e + 12 + sub];
      int c7 = lcol[e + 14 + sub];
      u32 v0 = *(const u32*)&zin[(size_t)c0 * 64 + 2 * fl];
      u32 v1 = *(const u32*)&zin[(size_t)c1 * 64 + 2 * fl];
      u32 v2 = *(const u32*)&zin[(size_t)c2 * 64 + 2 * fl];
      u32 v3 = *(const u32*)&zin[(size_t)c3 * 64 + 2 * fl];
      u32 v4 = *(const u32*)&zin[(size_t)c4 * 64 + 2 * fl];
      u32 v5 = *(const u32*)&zin[(size_t)c5 * 64 + 2 * fl];
      u32 v6 = *(const u32*)&zin[(size_t)c6 * 64 + 2 * fl];
      u32 v7 = *(const u32*)&zin[(size_t)c7 * 64 + 2 * fl];
      sa0 += __uint_as_float(v0 << 16);
      sb0 += __uint_as_float(v0 & 0xffff0000u);
      sa1 += __uint_as_float(v1 << 16);
      sb1 += __uint_as_float(v1 & 0xffff0000u);
      sa2 += __uint_as_float(v2 << 16);
      sb2 += __uint_as_float(v2 & 0xffff0000u);
      sa3 += __uint_as_float(v3 << 16);
      sb3 += __uint_as_float(v3 & 0xffff0000u);
      sa0 += __uint_as_float(v4 << 16);
      sb0 += __uint_as_float(v4 & 0xffff0000u);
      sa1 += __uint_as_float(v5 << 16);
      sb1 += __uint_as_float(v5 & 0xffff0000u);
      sa2 += __uint_as_float(v6 << 16);
      sb2 += __uint_as_float(v6 & 0xffff0000u);
      sa3 += __uint_as_float(v7 << 16);
      sb3 += __uint_as_float(v7 & 0xffff0000u);
    }
    float sa = (sa0 + sa1) + (sa2 + sa3);
    float sb = (sb0 + sb1) + (sb2 + sb3);
    sa += __shfl_xor(sa, 32);
    sb += __shfl_xor(sb, 32);
    float sum = sub ? sb : sa;
    float self = b2f(zin[(size_t)sn * 64 + f]);
    float h = fmaxf(sum + e1 * self + b1v, 0.f);
    H1[ln * HSTR + f] = f2b(h);
  }
  __syncthreads();  // lcol reads done block-wide; H1 fully written

  const int mrow = lane & 15;
  const int quad = lane >> 4;
  if (wv < 4) {
    f32x4 m1[4];
#pragma unroll
    for (int nt = 0; nt < 4; ++nt) {
      f32x4 acc = {0.f, 0.f, 0.f, 0.f};
#pragma unroll
      for (int ks = 0; ks < 2; ++ks) {
        short8 afr =
            *(const short8*)&H1[(wv * 16 + mrow) * HSTR + ks * 32 + quad * 8];
        short8 bfr = *(const short8*)&w2h[((nt * 2 + ks) * 64 + lane) * 8];
        acc = __builtin_amdgcn_mfma_f32_16x16x32_bf16(afr, bfr, acc, 0, 0, 0);
      }
      m1[nt] = acc;
    }
    LDS_FENCE();
#pragma unroll
    for (int nt = 0; nt < 4; ++nt) {
      float bb = b2s[nt * 16 + mrow];
#pragma unroll
      for (int r = 0; r < 4; ++r)
        H2[(wv * 16 + quad * 4 + r) * HSTR + nt * 16 + mrow] =
            f2b(fmaxf(m1[nt][r] + bb, 0.f));
    }
  }
  __syncthreads();  // H2 visible to all waves for pooling

  {
    const int n0p = wv * 8;
    float s = 0.f, m = 0.f;
    int cur = bt[n0p];
#pragma unroll 1
    for (int j = 0; j < 8; ++j) {
      int b = bt[n0p + j];
      if (b != cur) {
        if (cur >= 0) {
          atomicAdd(&p.gsum[cur * 192 + li * 64 + lane], s);
          atomicMax((u32*)&p.gmax[cur * 192 + li * 64 + lane],
                    __float_as_uint(m));
        }
        s = 0.f;
        m = 0.f;
        cur = b;
      }
      if (b >= 0) {
        float v = b2f(H2[(n0p + j) * HSTR + lane]);
        s += v;
        m = fmaxf(m, v);
      }
    }
    if (cur >= 0) {
      atomicAdd(&p.gsum[cur * 192 + li * 64 + lane], s);
      atomicMax((u32*)&p.gmax[cur * 192 + li * 64 + lane],
                __float_as_uint(m));
    }
  }

  if (hasnext) {
    __syncthreads();  // pooling reads of H2 done; H1 fully dead
    for (int i = tid; i < 512; i += NTHR)
      ((int4*)w1nh)[i] = ((const int4*)w1nf)[i];
    __syncthreads();
    if (wv < 4) {
      f32x4 m2[4];
#pragma unroll
      for (int nt = 0; nt < 4; ++nt) {
        f32x4 acc = {0.f, 0.f, 0.f, 0.f};
#pragma unroll
        for (int ks = 0; ks < 2; ++ks) {
          short8 afr =
              *(const short8*)&H2[(wv * 16 + mrow) * HSTR + ks * 32 + quad * 8];
          short8 bfr = *(const short8*)&w1nh[((nt * 2 + ks) * 64 + lane) * 8];
          acc = __builtin_amdgcn_mfma_f32_16x16x32_bf16(afr, bfr, acc, 0, 0, 0);
        }
        m2[nt] = acc;
      }
      LDS_FENCE();
#pragma unroll
      for (int nt = 0; nt < 4; ++nt)
#pragma unroll
        for (int r = 0; r < 4; ++r)
          H2[(wv * 16 + quad * 4 + r) * HSTR + nt * 16 + mrow] =
              f2b(m2[nt][r]);
    }
    __syncthreads();
    for (int i = tid; i < 2048; i += NTHR) {
      int n = i >> 5, kk = i & 31;
      int nn = base + n;
      if (nn < NNODES)
        *(u32*)&zn[(size_t)nn * 64 + 2 * kk] = *(u32*)&H2[n * HSTR + 2 * kk];
    }
  }
}

__device__ __forceinline__ void head_body(const GinParams& p, char* S,
                                          int vb) {
  float* gs = (float*)S;  // 8*576 floats = 18432 B
  const int tid = threadIdx.x;
  int g0 = vb * 8;
  for (int i = tid; i < 8 * 192; i += NTHR) {
    int w = i / 192, idx = i - w * 192;
    int gi = g0 + w;
    float Sv = p.gsum[gi * 192 + idx];
    float M = p.gmax[gi * 192 + idx];
    float C = (float)p.gcnt[gi];
    gs[w * 576 + idx] = Sv / fmaxf(C, 1.0f);
    gs[w * 576 + 192 + idx] = M;
    gs[w * 576 + 384 + idx] = Sv;
  }
  __syncthreads();
  int wv = tid >> 6, lane = tid & 63;
  int gi = g0 + wv;
  const float* grow = &gs[wv * 576];
  float acc = p.fc1b[lane];
#pragma unroll 8
  for (int k = 0; k < 576; ++k) acc += grow[k] * p.fc1w[k * 64 + lane];
  acc = fmaxf(acc, 0.f);
  float p0 = acc * p.fc2w[lane * 2 + 0];
  float p1 = acc * p.fc2w[lane * 2 + 1];
  for (int off = 32; off; off >>= 1) {
    p0 += __shfl_down(p0, off);
    p1 += __shfl_down(p1, off);
  }
  if (lane == 0) {
    p.out[gi * 2 + 0] = 1.f / (1.f + __expf(-(p0 + p.fc2b[0])));
    p.out[gi * 2 + 1] = 1.f / (1.f + __expf(-(p1 + p.fc2b[1])));
  }
}

// ---------------- kernels ----------------

// critical-path-only setup: w1f (needed by gemm) + gcur (needed by bin)
__global__ __launch_bounds__(NTHR) void setup_kernel(GinParams p) {
  const int tid = threadIdx.x;
  if (blockIdx.x == 0) {  // w1: 128x64 swizzle
    for (int i = tid; i < 8192; i += NTHR) {
      int jj = i & 7, lane = (i >> 3) & 63, c = i >> 9;
      int nt = c >> 2, ks = c & 3;
      int mrow = lane & 15, quad = lane >> 4;
      p.w1f[i] = f2b(p.w1g[(ks * 32 + quad * 8 + jj) * 64 + nt * 16 + mrow]);
    }
  } else {
    for (int i = tid; i < NB; i += NTHR) p.gcur[i] = 0;
  }
}

// bin (0..390) || gemm (391..1953) || extras (1954..2056)
__global__ __launch_bounds__(NTHR) void bingemm_kernel(GinParams p) {
  __shared__ __align__(16) char S[41472];
  if (blockIdx.x < NCHUNKS)
    bin_body(p, S, blockIdx.x);
  else if (blockIdx.x < NCHUNKS + NGEMM)
    gemm_body(p, S, blockIdx.x - NCHUNKS);
  else
    extra_body(p, blockIdx.x - (NCHUNKS + NGEMM));
}

// csr + agg layer 0 fused
__global__ __launch_bounds__(NTHR, 8) void aggcsr_kernel(GinParams p) {
  __shared__ __align__(16) char S[27648];
  const int tid = threadIdx.x;
  const int blk = blockIdx.x;
  int* lcol = (int*)S;
  int* lhist = (int*)(S + 9216);   // aliases H1 region (dead during csr)
  int* lcur = (int*)(S + 9472);
  int* ssc = (int*)(S + 9728);
  u16* w2h = (u16*)(S + 18432);
  float* b2s = (float*)(S + 26624);
  int* lofs = (int*)(S + 26880);   // agg's lofs; csr writes it clamped

  for (int i = tid; i < 512; i += NTHR)
    ((int4*)w2h)[i] = ((const int4*)p.w2f0)[i];
  if (tid < 64) b2s[tid] = p.b2_0[tid];

  const int bkt = blk >> 1;
  const int half = blk & 1;
  const int ofs = bkt * BCAP;
  const int cnt = min(p.gcur[bkt], BCAP);

  if (tid < 64) lhist[tid] = 0;
  __syncthreads();
  for (int i = tid; i < cnt; i += NTHR) {
    int d7 = p.st[ofs + i] & 127;
    if ((d7 >> 6) == half) atomicAdd(&lhist[d7 & 63], 1);
  }
  __syncthreads();
  if (tid < 64) ssc[tid] = (lhist[tid] + 15) & ~15;
  __syncthreads();
  for (int off = 1; off < 64; off <<= 1) {
    int v = (tid < 64 && tid >= off) ? ssc[tid - off] : 0;
    __syncthreads();
    if (tid < 64) ssc[tid] += v;
    __syncthreads();
  }
  if (tid < 64) {
    lofs[tid + 1] = min(ssc[tid], LCAP);
    lcur[tid] = ssc[tid] - ((lhist[tid] + 15) & ~15);
  }
  if (tid == 0) lofs[0] = 0;
  __syncthreads();
  for (int i = tid; i < cnt; i += NTHR) {
    int pkt = p.st[ofs + i];
    int d7 = pkt & 127;
    if ((d7 >> 6) == half) {
      int r = atomicAdd(&lcur[d7 & 63], 1);
      if (r < LCAP) lcol[r] = pkt >> 7;
    }
  }
  __syncthreads();
  if (tid < 64) {
    int re = lofs[tid + 1];  // already clamped
    for (int r = lcur[tid]; r < re; ++r) lcol[r] = NNODES;
  }
  __syncthreads();
  if (tid < 65) p.glofs[blk * GOFS + tid] = lofs[tid];
  {
    int L = lofs[64];
    int4* gdst = (int4*)(p.glcol + (size_t)blk * LCAP);
    const int4* lsrc = (const int4*)lcol;
    for (int i = tid; i < (L >> 2); i += NTHR) gdst[i] = lsrc[i];
  }
  agg_body<true>(p, S, blk, 0, p.zA, p.zB, p.b1_0, p.w1nf1, true);
}

template <bool HN>
__global__ __launch_bounds__(NTHR, 8) void agg_kernel(GinParams p, int li,
                                                      const u16* zin, u16* zn,
                                                      const float* b1p,
                                                      const u16* w1nf,
                                                      const u16* w2f,
                                                      const float* b2p) {
  __shared__ __align__(16) char S[27648];
  u16* w2h = (u16*)(S + 18432);
  float* b2s = (float*)(S + 26624);
  for (int i = threadIdx.x; i < 512; i += NTHR)
    ((int4*)w2h)[i] = ((const int4*)w2f)[i];
  if (threadIdx.x < 64) b2s[threadIdx.x] = b2p[threadIdx.x];
  __syncthreads();
  agg_body<false>(p, S, blockIdx.x, li, zin, zn, b1p, w1nf, HN);
}

__global__ __launch_bounds__(NTHR) void head_kernel(GinParams p) {
  __shared__ __align__(16) char S[18432];
  head_body(p, S, blockIdx.x);
}

// ---------------- launch ----------------

extern "C" void kernel_launch(void* const* d_in, const int* in_sizes, int n_in,
                              void* d_out, int out_size, void* d_ws,
                              size_t ws_size, hipStream_t stream) {
  const float* x = (const float*)d_in[0];
  const int* ei = (const int*)d_in[1];
  const int* src = ei;
  const int* dst = ei + NEDGES;
  const int* batch = (const int*)d_in[2];
  const float* lw1[3] = {(const float*)d_in[3], (const float*)d_in[7],
                         (const float*)d_in[11]};
  const float* lb1[3] = {(const float*)d_in[4], (const float*)d_in[8],
                         (const float*)d_in[12]};
  const float* lw2[3] = {(const float*)d_in[5], (const float*)d_in[9],
                         (const float*)d_in[13]};
  const float* lb2[3] = {(const float*)d_in[6], (const float*)d_in[10],
                         (const float*)d_in[14]};
  const float* eps = (const float*)d_in[15];
  const float* fc1w = (const float*)d_in[16];
  const float* fc1b = (const float*)d_in[17];
  const float* fc2w = (const float*)d_in[18];
  const float* fc2b = (const float*)d_in[19];
  float* out = (float*)d_out;

  char* p = (char*)d_ws;
  auto carve = [&](size_t bytes) {
    void* r = (void*)p;
    p += (bytes + 1023) & ~(size_t)1023;
    return r;
  };
  float* gsum = (float*)carve((size_t)NGRAPHS * 192 * 4);
  float* gmax = (float*)carve((size_t)NGRAPHS * 192 * 4);
  int* gcur = (int*)carve((NB + 4) * 4);
  int* st = (int*)carve((size_t)NB * BCAP * 4);
  int* glofs = (int*)carve((size_t)NBH * GOFS * 4);
  int* glcol = (int*)carve((size_t)NBH * LCAP * 4);
  u16* w1f = (u16*)carve(8192 * 2);
  u16* w2f0 = (u16*)carve(4096 * 2);
  u16* w2f1 = (u16*)carve(4096 * 2);
  u16* w2f2 = (u16*)carve(4096 * 2);
  u16* w1nf1 = (u16*)carve(4096 * 2);
  u16* w1nf2 = (u16*)carve(4096 * 2);
  u16* zA = (u16*)carve((size_t)(NNODES + 1) * 64 * 2);
  u16* zB = (u16*)carve((size_t)(NNODES + 1) * 64 * 2);
  int* gcnt = (int*)carve(NGRAPHS * 4);

  GinParams prm;
  prm.src = src; prm.dst = dst; prm.batch = batch; prm.x = x;
  prm.w1g = lw1[0]; prm.w2a = lw2[0]; prm.w2b = lw2[1]; prm.w2c = lw2[2];
  prm.w1b = lw1[1]; prm.w1c = lw1[2];
  prm.b1_0 = lb1[0]; prm.b1_1 = lb1[1]; prm.b1_2 = lb1[2];
  prm.b2_0 = lb2[0]; prm.b2_1 = lb2[1]; prm.b2_2 = lb2[2];
  prm.eps = eps;
  prm.fc1w = fc1w; prm.fc1b = fc1b; prm.fc2w = fc2w; prm.fc2b = fc2b;
  prm.out = out;
  prm.gcur = gcur; prm.st = st; prm.glofs = glofs; prm.glcol = glcol;
  prm.w1f = w1f; prm.w2f0 = w2f0; prm.w2f1 = w2f1; prm.w2f2 = w2f2;
  prm.w1nf1 = w1nf1; prm.w1nf2 = w1nf2;
  prm.zA = zA; prm.zB = zB; prm.gsum = gsum; prm.gmax = gmax; prm.gcnt = gcnt;

  setup_kernel<<<2, NTHR, 0, stream>>>(prm);
  bingemm_kernel<<<NCHUNKS + NGEMM + NEXTRA, NTHR, 0, stream>>>(prm);
  aggcsr_kernel<<<NBH, NTHR, 0, stream>>>(prm);
  agg_kernel<true><<<NBH, NTHR, 0, stream>>>(prm, 1, zB, zA, lb1[1], w1nf2,
                                             w2f1, lb2[1]);
  agg_kernel<false><<<NBH, NTHR, 0, stream>>>(prm, 2, zA, (u16*)nullptr,
                                              lb1[2], w1nf2, w2f2, lb2[2]);
  head_kernel<<<NGRAPHS / 8, NTHR, 0, stream>>>(prm);
}